// Round 11
// baseline (286.997 us; speedup 1.0000x reference)
//
#include <hip/hip_runtime.h>
#include <hip/hip_fp16.h>
#include <math.h>

#define N_NODES 50000
#define N_EDGES 800000
#define NGRAPH  1024
#define IN_DIM  25
#define DIM     64

// Direct binning: 782 buckets of 64 dst nodes. pack = (bkt<<22)|(col&63)<<16|row.
#define NBKB 782                   // ceil(N_NODES / 64)
#define CAP  1536                  // edges/bucket: mean 1024, sd 32 -> 16 sigma
#define EPB  4096                  // edges per binning block
#define NBIN 196                   // ceil(N_EDGES / EPB)
#define CROWS 128                  // set2set LDS row cache (mean 49, max ~84)

__device__ inline float wsum(float v) {
#pragma unroll
  for (int off = 32; off > 0; off >>= 1) v += __shfl_xor(v, off, 64);
  return v;
}
__device__ inline float sigmoidf(float x) { return 1.f / (1.f + expf(-x)); }

// ---- bin edges: LDS counting-sort per block -> coalesced bucket runs -----
__global__ __launch_bounds__(1024) void k_bin(const int* __restrict__ ei,
    int* __restrict__ gcur, int* __restrict__ pairs,
    const float* __restrict__ Wih, const float* __restrict__ Whh,
    float* __restrict__ WT) {
  __shared__ int hist[NBKB];
  __shared__ int sbase[NBKB];
  __shared__ int lbase[NBKB];
  __shared__ int sorted[EPB];
  int t = threadIdx.x;
  if (blockIdx.x == NBIN) {  // ---- LSTM weight transpose: WT[k][gate] ----
    for (int i = t; i < 3 * DIM * 4 * DIM; i += 1024) {
      int k = i >> 8, tt = i & 255;
      WT[i] = (k < 2 * DIM) ? Wih[tt * 2 * DIM + k] : Whh[tt * DIM + (k - 2 * DIM)];
    }
    return;
  }
  int base = blockIdx.x * EPB;
  for (int i = t; i < NBKB; i += 1024) hist[i] = 0;
  __syncthreads();
  int n = min(EPB, N_EDGES - base);   // multiple of 4 (tail = 1280)
  const int4* r4 = (const int4*)(ei + base);
  const int4* c4 = (const int4*)(ei + N_EDGES + base);
  int pk[4], bkt[4], rank[4];
  {
    bool ok = t * 4 < n;
    int4 rv, cv;
    if (ok) { rv = r4[t]; cv = c4[t]; }
#pragma unroll
    for (int u = 0; u < 4; u++) {
      if (ok) {
        int row = (&rv.x)[u], col = (&cv.x)[u];
        int b = col >> 6;
        bkt[u] = b;
        rank[u] = atomicAdd(&hist[b], 1);
        pk[u] = (int)(((unsigned)b << 22) | ((unsigned)(col & 63) << 16) | (unsigned)row);
      } else {
        bkt[u] = -1;
      }
    }
  }
  __syncthreads();
  // exclusive scan of hist (wave 0: 13 entries/lane covers 832 >= 782)
  if (t < 64) {
    int v[13];
    int loc = 0;
#pragma unroll
    for (int i = 0; i < 13; i++) {
      int idx = t * 13 + i;
      v[i] = (idx < NBKB) ? hist[idx] : 0;
      loc += v[i];
    }
    int x = loc;
#pragma unroll
    for (int d = 1; d < 64; d <<= 1) {
      int y = __shfl_up(x, d, 64);
      if (t >= d) x += y;
    }
    int excl = x - loc;
#pragma unroll
    for (int i = 0; i < 13; i++) {
      int idx = t * 13 + i;
      if (idx < NBKB) sbase[idx] = excl;
      excl += v[i];
    }
  }
  __syncthreads();
#pragma unroll
  for (int u = 0; u < 4; u++)
    if (bkt[u] >= 0) sorted[sbase[bkt[u]] + rank[u]] = pk[u];
  // gcur atomics: rotate sweep start per block to decorrelate the
  // cross-block contention bursts on the 782 global counters.
  {
    int offb = (blockIdx.x * 37) % NBKB;
    for (int ii = t; ii < NBKB; ii += 1024) {
      int i = ii + offb; if (i >= NBKB) i -= NBKB;
      lbase[i] = hist[i] ? atomicAdd(&gcur[i], hist[i]) : 0;
    }
  }
  __syncthreads();
  for (int i = t; i < n; i += 1024) {
    int p = sorted[i];
    int b = ((unsigned)p) >> 22;
    int gpos = lbase[b] + (i - sbase[b]);
    if (gpos < CAP) pairs[(size_t)b * CAP + gpos] = p & 0x3FFFFF;
  }
}

// ---- lin0 + relu + @Wc + degree hist (block == bucket of 64 nodes) -------
// LDS hist over this bucket's pairs; EXPORTS deg[] so k_agg needs no count
// pass. Stores hw16 = dinv[row]*result (fp16) and dinv[].
__global__ __launch_bounds__(256) void k_lin0(const float* __restrict__ x,
    const float* __restrict__ W0, const float* __restrict__ b0,
    const float* __restrict__ Wc, const int* __restrict__ pairs,
    const int* __restrict__ gcur, int* __restrict__ deg,
    float* __restrict__ dinv, __half* __restrict__ hw16) {
  __shared__ float sx[64][IN_DIM + 1];
  __shared__ float sW0[IN_DIM][DIM];
  __shared__ float sh[64][DIM + 4];
  __shared__ float sWc[DIM][DIM];
  __shared__ int histd[64];
  int t = threadIdx.x;
  int row0 = blockIdx.x * 64;
  if (t < 64) histd[t] = 0;
  __syncthreads();
  // stage tiles
  for (int i = t; i < 64 * IN_DIM; i += 256) {
    int r = i / IN_DIM, k = i - r * IN_DIM;
    int row = row0 + r;
    sx[r][k] = (row < N_NODES) ? x[row * IN_DIM + k] : 0.f;
  }
  for (int i = t; i < IN_DIM * DIM; i += 256) sW0[i >> 6][i & 63] = W0[i];
  for (int i = t; i < DIM * DIM; i += 256) sWc[i >> 6][i & 63] = Wc[i];
  // degree histogram for this bucket (col_local = bits 16..21 of pair)
  {
    int ne = min(gcur[blockIdx.x], CAP);
    const int* pp = pairs + (size_t)blockIdx.x * CAP;
    const int4* pp4 = (const int4*)pp;
    int ne4 = ne >> 2;
    for (int i = t; i < ne4; i += 256) {
      int4 p4 = pp4[i];
      atomicAdd(&histd[(p4.x >> 16) & 63], 1);
      atomicAdd(&histd[(p4.y >> 16) & 63], 1);
      atomicAdd(&histd[(p4.z >> 16) & 63], 1);
      atomicAdd(&histd[(p4.w >> 16) & 63], 1);
    }
    for (int i = (ne4 << 2) + t; i < ne; i += 256)
      atomicAdd(&histd[(pp[i] >> 16) & 63], 1);
  }
  __syncthreads();
  int tc = (t & 15) * 4;
  int tr = (t >> 4) * 4;
  float acc[4][4];
  {
    float4 bb = *(const float4*)&b0[tc];
#pragma unroll
    for (int i = 0; i < 4; i++) {
      acc[i][0] = bb.x; acc[i][1] = bb.y; acc[i][2] = bb.z; acc[i][3] = bb.w;
    }
  }
#pragma unroll
  for (int k = 0; k < IN_DIM; k++) {
    float4 w = *(const float4*)&sW0[k][tc];
#pragma unroll
    for (int i = 0; i < 4; i++) {
      float a = sx[tr + i][k];
      acc[i][0] += a * w.x; acc[i][1] += a * w.y;
      acc[i][2] += a * w.z; acc[i][3] += a * w.w;
    }
  }
#pragma unroll
  for (int i = 0; i < 4; i++) {
    sh[tr + i][tc + 0] = fmaxf(acc[i][0], 0.f);
    sh[tr + i][tc + 1] = fmaxf(acc[i][1], 0.f);
    sh[tr + i][tc + 2] = fmaxf(acc[i][2], 0.f);
    sh[tr + i][tc + 3] = fmaxf(acc[i][3], 0.f);
  }
  __syncthreads();
#pragma unroll
  for (int i = 0; i < 4; i++) acc[i][0] = acc[i][1] = acc[i][2] = acc[i][3] = 0.f;
#pragma unroll 8
  for (int k = 0; k < DIM; k++) {
    float4 w = *(const float4*)&sWc[k][tc];
#pragma unroll
    for (int i = 0; i < 4; i++) {
      float a = sh[tr + i][k];
      acc[i][0] += a * w.x; acc[i][1] += a * w.y;
      acc[i][2] += a * w.z; acc[i][3] += a * w.w;
    }
  }
  if (t < 64) {
    int node = row0 + t;
    if (node < N_NODES) {
      deg[node] = histd[t];
      dinv[node] = rsqrtf((float)(histd[t] + 1));
    }
  }
  float2* hwf2 = (float2*)hw16;
#pragma unroll
  for (int i = 0; i < 4; i++) {
    int row = row0 + tr + i;
    if (row < N_NODES) {
      float dv = rsqrtf((float)(histd[tr + i] + 1));
      float2 st;
      ((__half2*)&st)[0] = __floats2half2_rn(acc[i][0] * dv, acc[i][1] * dv);
      ((__half2*)&st)[1] = __floats2half2_rn(acc[i][2] * dv, acc[i][3] * dv);
      hwf2[(size_t)row * 16 + (t & 15)] = st;
    }
  }
}

// ---- GCN aggregate: deg-seeded scan -> LDS per-node lists -> node-driven
// register-accumulating gather. 1024 threads (16 waves), VGPR<=64 via
// launch_bounds -> 2 blocks/CU = 32 waves/CU (occupancy cap) for gather MLP.
__global__ __launch_bounds__(1024, 8) void k_agg(const int* __restrict__ pairs,
    const int* __restrict__ gcur, const int* __restrict__ deg,
    const __half* __restrict__ hw16, const float* __restrict__ dinv,
    const float4* __restrict__ bc4, __half* __restrict__ h16) {
  __shared__ unsigned short rows[CAP];  // 3 KiB: row indices sorted by dst
  __shared__ int off[65];
  __shared__ int cur[64];
  int b = blockIdx.x, t = threadIdx.x;
  int lane = t & 63, wave = t >> 6, q = lane >> 4, ql = lane & 15;
  int qid = (wave << 2) + q;  // quarter-wave id, 0..63: one node each
  // per-node counts straight from deg (bucket sum == gcur[b])
  if (t < 64) {
    int node = b * 64 + t;
    int v = (node < N_NODES) ? deg[node] : 0;
    int x = v;
#pragma unroll
    for (int d = 1; d < 64; d <<= 1) {
      int y = __shfl_up(x, d, 64);
      if (t >= d) x += y;
    }
    off[t] = x - v;
    cur[t] = x - v;
    if (t == 63) off[64] = x;
  }
  __syncthreads();
  int ne = min(gcur[b], CAP);
  const int* pp = pairs + (size_t)b * CAP;
  const int4* pp4 = (const int4*)pp;
  int ne4 = ne >> 2;
  // scatter row indices into per-node runs
  for (int i = t; i < ne4; i += 1024) {
    int4 p4 = pp4[i];
#pragma unroll
    for (int u = 0; u < 4; u++) {
      int p = (&p4.x)[u];
      int slot = atomicAdd(&cur[(p >> 16) & 63], 1);
      if (slot < CAP) rows[slot] = (unsigned short)(p & 0xFFFF);
    }
  }
  for (int i = (ne4 << 2) + t; i < ne; i += 1024) {
    int p = pp[i];
    int slot = atomicAdd(&cur[(p >> 16) & 63], 1);
    if (slot < CAP) rows[slot] = (unsigned short)(p & 0xFFFF);
  }
  __syncthreads();
  // node-driven gather: quarter-wave per node, 8 loads in flight
  const float2* hwf2 = (const float2*)hw16;
  float4 bb = bc4[ql];
  for (int nl = qid; nl < 64; nl += 64) {
    int node = b * 64 + nl;
    if (node >= N_NODES) continue;
    int s0 = off[nl], e0 = min(off[nl + 1], CAP);
    float4 a0, a1, a2, a3;
    {  // self loop (already dinv[node]-scaled)
      float2 raw = hwf2[(size_t)node * 16 + ql];
      float2 f0 = __half22float2(((const __half2*)&raw)[0]);
      float2 f1 = __half22float2(((const __half2*)&raw)[1]);
      a0 = make_float4(f0.x, f0.y, f1.x, f1.y);
      a1 = make_float4(0.f, 0.f, 0.f, 0.f); a2 = a1; a3 = a1;
    }
    int j = s0;
    for (; j + 8 <= e0; j += 8) {
      int r0 = rows[j], r1 = rows[j + 1], r2 = rows[j + 2], r3 = rows[j + 3];
      int r4_ = rows[j + 4], r5 = rows[j + 5], r6 = rows[j + 6], r7 = rows[j + 7];
      float2 w0 = hwf2[(size_t)r0 * 16 + ql];
      float2 w1 = hwf2[(size_t)r1 * 16 + ql];
      float2 w2 = hwf2[(size_t)r2 * 16 + ql];
      float2 w3 = hwf2[(size_t)r3 * 16 + ql];
      float2 w4 = hwf2[(size_t)r4_ * 16 + ql];
      float2 w5 = hwf2[(size_t)r5 * 16 + ql];
      float2 w6 = hwf2[(size_t)r6 * 16 + ql];
      float2 w7 = hwf2[(size_t)r7 * 16 + ql];
      float2 f;
      f = __half22float2(((const __half2*)&w0)[0]); a0.x += f.x; a0.y += f.y;
      f = __half22float2(((const __half2*)&w0)[1]); a0.z += f.x; a0.w += f.y;
      f = __half22float2(((const __half2*)&w1)[0]); a1.x += f.x; a1.y += f.y;
      f = __half22float2(((const __half2*)&w1)[1]); a1.z += f.x; a1.w += f.y;
      f = __half22float2(((const __half2*)&w2)[0]); a2.x += f.x; a2.y += f.y;
      f = __half22float2(((const __half2*)&w2)[1]); a2.z += f.x; a2.w += f.y;
      f = __half22float2(((const __half2*)&w3)[0]); a3.x += f.x; a3.y += f.y;
      f = __half22float2(((const __half2*)&w3)[1]); a3.z += f.x; a3.w += f.y;
      f = __half22float2(((const __half2*)&w4)[0]); a0.x += f.x; a0.y += f.y;
      f = __half22float2(((const __half2*)&w4)[1]); a0.z += f.x; a0.w += f.y;
      f = __half22float2(((const __half2*)&w5)[0]); a1.x += f.x; a1.y += f.y;
      f = __half22float2(((const __half2*)&w5)[1]); a1.z += f.x; a1.w += f.y;
      f = __half22float2(((const __half2*)&w6)[0]); a2.x += f.x; a2.y += f.y;
      f = __half22float2(((const __half2*)&w6)[1]); a2.z += f.x; a2.w += f.y;
      f = __half22float2(((const __half2*)&w7)[0]); a3.x += f.x; a3.y += f.y;
      f = __half22float2(((const __half2*)&w7)[1]); a3.z += f.x; a3.w += f.y;
    }
    for (; j + 4 <= e0; j += 4) {
      int r0 = rows[j], r1 = rows[j + 1], r2 = rows[j + 2], r3 = rows[j + 3];
      float2 w0 = hwf2[(size_t)r0 * 16 + ql];
      float2 w1 = hwf2[(size_t)r1 * 16 + ql];
      float2 w2 = hwf2[(size_t)r2 * 16 + ql];
      float2 w3 = hwf2[(size_t)r3 * 16 + ql];
      float2 f;
      f = __half22float2(((const __half2*)&w0)[0]); a0.x += f.x; a0.y += f.y;
      f = __half22float2(((const __half2*)&w0)[1]); a0.z += f.x; a0.w += f.y;
      f = __half22float2(((const __half2*)&w1)[0]); a1.x += f.x; a1.y += f.y;
      f = __half22float2(((const __half2*)&w1)[1]); a1.z += f.x; a1.w += f.y;
      f = __half22float2(((const __half2*)&w2)[0]); a2.x += f.x; a2.y += f.y;
      f = __half22float2(((const __half2*)&w2)[1]); a2.z += f.x; a2.w += f.y;
      f = __half22float2(((const __half2*)&w3)[0]); a3.x += f.x; a3.y += f.y;
      f = __half22float2(((const __half2*)&w3)[1]); a3.z += f.x; a3.w += f.y;
    }
    for (; j < e0; j++) {
      int r = rows[j];
      float2 w = hwf2[(size_t)r * 16 + ql];
      float2 f;
      f = __half22float2(((const __half2*)&w)[0]); a0.x += f.x; a0.y += f.y;
      f = __half22float2(((const __half2*)&w)[1]); a0.z += f.x; a0.w += f.y;
    }
    float di = dinv[node];
    float ox = fmaxf(((a0.x + a1.x) + (a2.x + a3.x)) * di + bb.x, 0.f);
    float oy = fmaxf(((a0.y + a1.y) + (a2.y + a3.y)) * di + bb.y, 0.f);
    float oz = fmaxf(((a0.z + a1.z) + (a2.z + a3.z)) * di + bb.z, 0.f);
    float ow = fmaxf(((a0.w + a1.w) + (a2.w + a3.w)) * di + bb.w, 0.f);
    float2 st;
    ((__half2*)&st)[0] = __floats2half2_rn(ox, oy);
    ((__half2*)&st)[1] = __floats2half2_rn(oz, ow);
    ((float2*)h16)[(size_t)node * 16 + ql] = st;
  }
}

// ---- fused Set2Set: 1 graph/block (1024 blocks -> 4 blocks/CU TLP) -------
__global__ __launch_bounds__(256) void k_set2set(
    const __half* __restrict__ h16, const int* __restrict__ batch,
    const float* __restrict__ WT, const float* __restrict__ bih,
    const float* __restrict__ bhh, const float* __restrict__ W1,
    const float* __restrict__ b1, const float* __restrict__ W2,
    const float* __restrict__ b2, float* __restrict__ out) {
  int b = blockIdx.x, t = threadIdx.x;
  int wave = t >> 6, lane = t & 63;
  int q = lane >> 4, ql = lane & 15;
  int qid = (wave << 2) + q;  // 0..15
  __shared__ float2 hcf2[CROWS * 16];  // 16 KiB fp16 row cache
  __shared__ float qs[2 * DIM];
  __shared__ float hsl[DIM], csl[DIM];
  __shared__ float gates[4 * DIM];
  __shared__ float red[16 * DIM];
  __shared__ float lred[16], wmax[16];
  __shared__ int seg[2];
  const float2* h2 = (const float2*)h16;
  if (t < 2) {  // graph boundary via binary search on sorted batch
    int g = b + t;
    int lo = 0, hi = N_NODES;
    if (g == NGRAPH) lo = N_NODES;
    else while (lo < hi) { int mid = (lo + hi) >> 1; if (batch[mid] < g) lo = mid + 1; else hi = mid; }
    seg[t] = lo;
  }
  if (t < 2 * DIM) qs[t] = 0.f;
  if (t < DIM) { hsl[t] = 0.f; csl[t] = 0.f; }
  __syncthreads();
  int s = seg[0], eend = seg[1];
  int nc = min(eend - s, CROWS);
  for (int i = t; i < nc * 16; i += 256)
    hcf2[i] = h2[(size_t)(s + (i >> 4)) * 16 + (i & 15)];
  __syncthreads();
  float bsum = bih[t] + bhh[t];
  for (int step = 0; step < 3; step++) {
    // ---- LSTM cell: thread t computes gate t (coalesced WT reads) ----
    float g = bsum;
    if (step > 0) {  // step 0: q_star = hs = 0 -> matmul contributes nothing
      const float* wp = WT + t;
      float g1 = 0.f;
#pragma unroll
      for (int k = 0; k < 2 * DIM; k += 2) {
        g += qs[k] * wp[k * 4 * DIM];
        g1 += qs[k + 1] * wp[(k + 1) * 4 * DIM];
      }
#pragma unroll
      for (int k = 0; k < DIM; k += 2) {
        g += hsl[k] * wp[(2 * DIM + k) * 4 * DIM];
        g1 += hsl[k + 1] * wp[(2 * DIM + k + 1) * 4 * DIM];
      }
      g += g1;
    }
    gates[t] = g;
    __syncthreads();
    if (t < DIM) {
      float ig = sigmoidf(gates[t]);
      float fg = sigmoidf(gates[DIM + t]);
      float gg = tanhf(gates[2 * DIM + t]);
      float og = sigmoidf(gates[3 * DIM + t]);
      float c = fg * csl[t] + ig * gg;
      csl[t] = c;
      float hh = og * tanhf(c);
      hsl[t] = hh;
      qs[t] = hh;  // q half of q_star
    }
    __syncthreads();
    // ---- quarter-wave online softmax over LDS-cached rows ----
    float4 qf = *(const float4*)&hsl[4 * ql];
    float m_w = -INFINITY, l_w = 0.f;
    float4 racc = make_float4(0.f, 0.f, 0.f, 0.f);
    for (int j = s + qid; j < eend; j += 16) {
      int lj = j - s;
      float2 raw = (lj < CROWS) ? hcf2[lj * 16 + ql]
                                : h2[(size_t)j * 16 + ql];
      float2 f0 = __half22float2(((const __half2*)&raw)[0]);
      float2 f1 = __half22float2(((const __half2*)&raw)[1]);
      float p = f0.x * qf.x + f0.y * qf.y + f1.x * qf.z + f1.y * qf.w;
#pragma unroll
      for (int off = 1; off < 16; off <<= 1) p += __shfl_xor(p, off, 64);
      float m_new = fmaxf(m_w, p);
      float scale = __expf(m_w - m_new);  // first row: exp(-inf)=0
      float a = __expf(p - m_new);
      racc.x = racc.x * scale + a * f0.x;
      racc.y = racc.y * scale + a * f0.y;
      racc.z = racc.z * scale + a * f1.x;
      racc.w = racc.w * scale + a * f1.y;
      l_w = l_w * scale + a;
      m_w = m_new;
    }
    *(float4*)&red[qid * DIM + 4 * ql] = racc;
    if (ql == 0) { lred[qid] = l_w; wmax[qid] = m_w; }
    __syncthreads();
    if (t < DIM) {
      float m_b = -1e30f;  // floor avoids NaN for empty graphs
      for (int i = 0; i < 16; i++) m_b = fmaxf(m_b, wmax[i]);
      float r = 0.f, l = 0.f;
      for (int i = 0; i < 16; i++) {
        float e = __expf(wmax[i] - m_b);
        r += red[i * DIM + t] * e;
        l += lred[i] * e;
      }
      qs[DIM + t] = (l > 0.f) ? r / l : 0.f;
    }
    __syncthreads();
  }
  // ---- output MLP head ----
  if (t < DIM) {
    float acc = b1[t];
#pragma unroll
    for (int k = 0; k < 2 * DIM; k++) acc += qs[k] * W1[k * DIM + t];
    acc = fmaxf(acc, 0.f);
    float v = wsum(acc * W2[t]);
    if (t == 0) out[b] = v + b2[0];
  }
}

extern "C" void kernel_launch(void* const* d_in, const int* in_sizes, int n_in,
                              void* d_out, int out_size, void* d_ws, size_t ws_size,
                              hipStream_t stream) {
  const float* x    = (const float*)d_in[0];
  const int*   ei   = (const int*)d_in[1];
  const int*   batch= (const int*)d_in[2];
  const float* W0   = (const float*)d_in[3];
  const float* b0   = (const float*)d_in[4];
  const float* Wc   = (const float*)d_in[5];
  const float* bc   = (const float*)d_in[6];
  const float* Wih  = (const float*)d_in[7];
  const float* Whh  = (const float*)d_in[8];
  const float* bih  = (const float*)d_in[9];
  const float* bhh  = (const float*)d_in[10];
  const float* W1   = (const float*)d_in[11];
  const float* b1   = (const float*)d_in[12];
  const float* W2   = (const float*)d_in[13];
  const float* b2   = (const float*)d_in[14];
  float* out = (float*)d_out;

  __half* hw16 = (__half*)d_ws;                      // N*DIM halves (6.4 MB)
  __half* h16  = hw16 + (size_t)N_NODES * DIM;       // N*DIM halves (6.4 MB)
  float* dinv  = (float*)(h16 + (size_t)N_NODES * DIM);  // N floats
  float* WT    = dinv + N_NODES;                     // 192*256 floats
  int* gcur    = (int*)(WT + 3 * DIM * 4 * DIM);     // NBKB bucket counters
  int* deg     = gcur + NBKB;                        // N per-node in-degree
  int* pairs   = deg + N_NODES + 2;                  // NBKB*CAP packed edges (16B-aligned)

  hipMemsetAsync(gcur, 0, NBKB * sizeof(int), stream);
  k_bin<<<NBIN + 1, 1024, 0, stream>>>(ei, gcur, pairs, Wih, Whh, WT);
  k_lin0<<<NBKB, 256, 0, stream>>>(x, W0, b0, Wc, pairs, gcur, deg, dinv, hw16);
  k_agg<<<NBKB, 1024, 0, stream>>>(pairs, gcur, deg, hw16, dinv, (const float4*)bc, h16);
  k_set2set<<<NGRAPH, 256, 0, stream>>>(h16, batch, WT, bih, bhh, W1, b1, W2, b2, out);
}

// Round 12
// 186.208 us; speedup vs baseline: 1.5413x; 1.5413x over previous
//
#include <hip/hip_runtime.h>
#include <hip/hip_fp16.h>
#include <math.h>

#define N_NODES 50000
#define N_EDGES 800000
#define NGRAPH  1024
#define IN_DIM  25
#define DIM     64

// Direct binning: 782 buckets of 64 dst nodes. pack = (bkt<<22)|(col&63)<<16|row.
#define NBKB 782                   // ceil(N_NODES / 64)
#define CAP  1536                  // edges/bucket: mean 1024, sd 32 -> 16 sigma
#define EPB  4096                  // edges per binning block
#define NBIN 196                   // ceil(N_EDGES / EPB)
#define CROWS 128                  // set2set LDS row cache (mean 49, max ~84)

__device__ inline float wsum(float v) {
#pragma unroll
  for (int off = 32; off > 0; off >>= 1) v += __shfl_xor(v, off, 64);
  return v;
}
__device__ inline float sigmoidf(float x) { return 1.f / (1.f + expf(-x)); }

// ---- bin edges: LDS counting-sort per block -> coalesced bucket runs -----
__global__ __launch_bounds__(1024) void k_bin(const int* __restrict__ ei,
    int* __restrict__ gcur, int* __restrict__ pairs,
    const float* __restrict__ Wih, const float* __restrict__ Whh,
    float* __restrict__ WT) {
  __shared__ int hist[NBKB];
  __shared__ int sbase[NBKB];
  __shared__ int lbase[NBKB];
  __shared__ int sorted[EPB];
  int t = threadIdx.x;
  if (blockIdx.x == NBIN) {  // ---- LSTM weight transpose: WT[k][gate] ----
    for (int i = t; i < 3 * DIM * 4 * DIM; i += 1024) {
      int k = i >> 8, tt = i & 255;
      WT[i] = (k < 2 * DIM) ? Wih[tt * 2 * DIM + k] : Whh[tt * DIM + (k - 2 * DIM)];
    }
    return;
  }
  int base = blockIdx.x * EPB;
  for (int i = t; i < NBKB; i += 1024) hist[i] = 0;
  __syncthreads();
  int n = min(EPB, N_EDGES - base);   // multiple of 4 (tail = 1280)
  const int4* r4 = (const int4*)(ei + base);
  const int4* c4 = (const int4*)(ei + N_EDGES + base);
  int pk[4], bkt[4], rank[4];
  {
    bool ok = t * 4 < n;
    int4 rv, cv;
    if (ok) { rv = r4[t]; cv = c4[t]; }
#pragma unroll
    for (int u = 0; u < 4; u++) {
      if (ok) {
        int row = (&rv.x)[u], col = (&cv.x)[u];
        int b = col >> 6;
        bkt[u] = b;
        rank[u] = atomicAdd(&hist[b], 1);
        pk[u] = (int)(((unsigned)b << 22) | ((unsigned)(col & 63) << 16) | (unsigned)row);
      } else {
        bkt[u] = -1;
      }
    }
  }
  __syncthreads();
  // exclusive scan of hist (wave 0: 13 entries/lane covers 832 >= 782)
  if (t < 64) {
    int v[13];
    int loc = 0;
#pragma unroll
    for (int i = 0; i < 13; i++) {
      int idx = t * 13 + i;
      v[i] = (idx < NBKB) ? hist[idx] : 0;
      loc += v[i];
    }
    int x = loc;
#pragma unroll
    for (int d = 1; d < 64; d <<= 1) {
      int y = __shfl_up(x, d, 64);
      if (t >= d) x += y;
    }
    int excl = x - loc;
#pragma unroll
    for (int i = 0; i < 13; i++) {
      int idx = t * 13 + i;
      if (idx < NBKB) sbase[idx] = excl;
      excl += v[i];
    }
  }
  __syncthreads();
#pragma unroll
  for (int u = 0; u < 4; u++)
    if (bkt[u] >= 0) sorted[sbase[bkt[u]] + rank[u]] = pk[u];
  for (int i = t; i < NBKB; i += 1024)
    lbase[i] = hist[i] ? atomicAdd(&gcur[i], hist[i]) : 0;
  __syncthreads();
  for (int i = t; i < n; i += 1024) {
    int p = sorted[i];
    int b = ((unsigned)p) >> 22;
    int gpos = lbase[b] + (i - sbase[b]);
    if (gpos < CAP) pairs[(size_t)b * CAP + gpos] = p & 0x3FFFFF;
  }
}

// ---- lin0 + relu + @Wc + degree hist (block == bucket of 64 nodes) -------
// LDS hist over this bucket's pairs; EXPORTS deg[] so k_agg needs no count
// pass. Stores hw16 = dinv[row]*result (fp16) and dinv[].
__global__ __launch_bounds__(256) void k_lin0(const float* __restrict__ x,
    const float* __restrict__ W0, const float* __restrict__ b0,
    const float* __restrict__ Wc, const int* __restrict__ pairs,
    const int* __restrict__ gcur, int* __restrict__ deg,
    float* __restrict__ dinv, __half* __restrict__ hw16) {
  __shared__ float sx[64][IN_DIM + 1];
  __shared__ float sW0[IN_DIM][DIM];
  __shared__ float sh[64][DIM + 4];
  __shared__ float sWc[DIM][DIM];
  __shared__ int histd[64];
  int t = threadIdx.x;
  int row0 = blockIdx.x * 64;
  if (t < 64) histd[t] = 0;
  __syncthreads();
  // stage tiles
  for (int i = t; i < 64 * IN_DIM; i += 256) {
    int r = i / IN_DIM, k = i - r * IN_DIM;
    int row = row0 + r;
    sx[r][k] = (row < N_NODES) ? x[row * IN_DIM + k] : 0.f;
  }
  for (int i = t; i < IN_DIM * DIM; i += 256) sW0[i >> 6][i & 63] = W0[i];
  for (int i = t; i < DIM * DIM; i += 256) sWc[i >> 6][i & 63] = Wc[i];
  // degree histogram for this bucket (col_local = bits 16..21 of pair)
  {
    int ne = min(gcur[blockIdx.x], CAP);
    const int* pp = pairs + (size_t)blockIdx.x * CAP;
    const int4* pp4 = (const int4*)pp;
    int ne4 = ne >> 2;
    for (int i = t; i < ne4; i += 256) {
      int4 p4 = pp4[i];
      atomicAdd(&histd[(p4.x >> 16) & 63], 1);
      atomicAdd(&histd[(p4.y >> 16) & 63], 1);
      atomicAdd(&histd[(p4.z >> 16) & 63], 1);
      atomicAdd(&histd[(p4.w >> 16) & 63], 1);
    }
    for (int i = (ne4 << 2) + t; i < ne; i += 256)
      atomicAdd(&histd[(pp[i] >> 16) & 63], 1);
  }
  __syncthreads();
  int tc = (t & 15) * 4;
  int tr = (t >> 4) * 4;
  float acc[4][4];
  {
    float4 bb = *(const float4*)&b0[tc];
#pragma unroll
    for (int i = 0; i < 4; i++) {
      acc[i][0] = bb.x; acc[i][1] = bb.y; acc[i][2] = bb.z; acc[i][3] = bb.w;
    }
  }
#pragma unroll
  for (int k = 0; k < IN_DIM; k++) {
    float4 w = *(const float4*)&sW0[k][tc];
#pragma unroll
    for (int i = 0; i < 4; i++) {
      float a = sx[tr + i][k];
      acc[i][0] += a * w.x; acc[i][1] += a * w.y;
      acc[i][2] += a * w.z; acc[i][3] += a * w.w;
    }
  }
#pragma unroll
  for (int i = 0; i < 4; i++) {
    sh[tr + i][tc + 0] = fmaxf(acc[i][0], 0.f);
    sh[tr + i][tc + 1] = fmaxf(acc[i][1], 0.f);
    sh[tr + i][tc + 2] = fmaxf(acc[i][2], 0.f);
    sh[tr + i][tc + 3] = fmaxf(acc[i][3], 0.f);
  }
  __syncthreads();
#pragma unroll
  for (int i = 0; i < 4; i++) acc[i][0] = acc[i][1] = acc[i][2] = acc[i][3] = 0.f;
#pragma unroll 8
  for (int k = 0; k < DIM; k++) {
    float4 w = *(const float4*)&sWc[k][tc];
#pragma unroll
    for (int i = 0; i < 4; i++) {
      float a = sh[tr + i][k];
      acc[i][0] += a * w.x; acc[i][1] += a * w.y;
      acc[i][2] += a * w.z; acc[i][3] += a * w.w;
    }
  }
  if (t < 64) {
    int node = row0 + t;
    if (node < N_NODES) {
      deg[node] = histd[t];
      dinv[node] = rsqrtf((float)(histd[t] + 1));
    }
  }
  float2* hwf2 = (float2*)hw16;
#pragma unroll
  for (int i = 0; i < 4; i++) {
    int row = row0 + tr + i;
    if (row < N_NODES) {
      float dv = rsqrtf((float)(histd[tr + i] + 1));
      float2 st;
      ((__half2*)&st)[0] = __floats2half2_rn(acc[i][0] * dv, acc[i][1] * dv);
      ((__half2*)&st)[1] = __floats2half2_rn(acc[i][2] * dv, acc[i][3] * dv);
      hwf2[(size_t)row * 16 + (t & 15)] = st;
    }
  }
}

// ---- GCN aggregate: deg-seeded scan -> LDS per-node lists -> node-driven
// register-accumulating gather. 512 threads (8 waves): 32 quarter-waves,
// 2 nodes each -> ~24 waves/CU to hide L2/L3 gather latency.
__global__ __launch_bounds__(512) void k_agg(const int* __restrict__ pairs,
    const int* __restrict__ gcur, const int* __restrict__ deg,
    const __half* __restrict__ hw16, const float* __restrict__ dinv,
    const float4* __restrict__ bc4, __half* __restrict__ h16) {
  __shared__ unsigned short rows[CAP];  // 3 KiB: row indices sorted by dst
  __shared__ int off[65];
  __shared__ int cur[64];
  int b = blockIdx.x, t = threadIdx.x;
  int lane = t & 63, wave = t >> 6, q = lane >> 4, ql = lane & 15;
  int qid = (wave << 2) + q;  // quarter-wave id, 0..31
  // per-node counts straight from deg (bucket sum == gcur[b])
  if (t < 64) {
    int node = b * 64 + t;
    int v = (node < N_NODES) ? deg[node] : 0;
    int x = v;
#pragma unroll
    for (int d = 1; d < 64; d <<= 1) {
      int y = __shfl_up(x, d, 64);
      if (t >= d) x += y;
    }
    off[t] = x - v;
    cur[t] = x - v;
    if (t == 63) off[64] = x;
  }
  __syncthreads();
  int ne = min(gcur[b], CAP);
  const int* pp = pairs + (size_t)b * CAP;
  const int4* pp4 = (const int4*)pp;
  int ne4 = ne >> 2;
  // scatter row indices into per-node runs
  for (int i = t; i < ne4; i += 512) {
    int4 p4 = pp4[i];
#pragma unroll
    for (int u = 0; u < 4; u++) {
      int p = (&p4.x)[u];
      int slot = atomicAdd(&cur[(p >> 16) & 63], 1);
      if (slot < CAP) rows[slot] = (unsigned short)(p & 0xFFFF);
    }
  }
  for (int i = (ne4 << 2) + t; i < ne; i += 512) {
    int p = pp[i];
    int slot = atomicAdd(&cur[(p >> 16) & 63], 1);
    if (slot < CAP) rows[slot] = (unsigned short)(p & 0xFFFF);
  }
  __syncthreads();
  // node-driven gather: quarter-wave per node, 8 loads in flight
  const float2* hwf2 = (const float2*)hw16;
  float4 bb = bc4[ql];
  for (int nl = qid; nl < 64; nl += 32) {
    int node = b * 64 + nl;
    if (node >= N_NODES) continue;
    int s0 = off[nl], e0 = min(off[nl + 1], CAP);
    float4 a0, a1, a2, a3;
    {  // self loop (already dinv[node]-scaled)
      float2 raw = hwf2[(size_t)node * 16 + ql];
      float2 f0 = __half22float2(((const __half2*)&raw)[0]);
      float2 f1 = __half22float2(((const __half2*)&raw)[1]);
      a0 = make_float4(f0.x, f0.y, f1.x, f1.y);
      a1 = make_float4(0.f, 0.f, 0.f, 0.f); a2 = a1; a3 = a1;
    }
    int j = s0;
    for (; j + 8 <= e0; j += 8) {
      int r0 = rows[j], r1 = rows[j + 1], r2 = rows[j + 2], r3 = rows[j + 3];
      int r4_ = rows[j + 4], r5 = rows[j + 5], r6 = rows[j + 6], r7 = rows[j + 7];
      float2 w0 = hwf2[(size_t)r0 * 16 + ql];
      float2 w1 = hwf2[(size_t)r1 * 16 + ql];
      float2 w2 = hwf2[(size_t)r2 * 16 + ql];
      float2 w3 = hwf2[(size_t)r3 * 16 + ql];
      float2 w4 = hwf2[(size_t)r4_ * 16 + ql];
      float2 w5 = hwf2[(size_t)r5 * 16 + ql];
      float2 w6 = hwf2[(size_t)r6 * 16 + ql];
      float2 w7 = hwf2[(size_t)r7 * 16 + ql];
      float2 f;
      f = __half22float2(((const __half2*)&w0)[0]); a0.x += f.x; a0.y += f.y;
      f = __half22float2(((const __half2*)&w0)[1]); a0.z += f.x; a0.w += f.y;
      f = __half22float2(((const __half2*)&w1)[0]); a1.x += f.x; a1.y += f.y;
      f = __half22float2(((const __half2*)&w1)[1]); a1.z += f.x; a1.w += f.y;
      f = __half22float2(((const __half2*)&w2)[0]); a2.x += f.x; a2.y += f.y;
      f = __half22float2(((const __half2*)&w2)[1]); a2.z += f.x; a2.w += f.y;
      f = __half22float2(((const __half2*)&w3)[0]); a3.x += f.x; a3.y += f.y;
      f = __half22float2(((const __half2*)&w3)[1]); a3.z += f.x; a3.w += f.y;
      f = __half22float2(((const __half2*)&w4)[0]); a0.x += f.x; a0.y += f.y;
      f = __half22float2(((const __half2*)&w4)[1]); a0.z += f.x; a0.w += f.y;
      f = __half22float2(((const __half2*)&w5)[0]); a1.x += f.x; a1.y += f.y;
      f = __half22float2(((const __half2*)&w5)[1]); a1.z += f.x; a1.w += f.y;
      f = __half22float2(((const __half2*)&w6)[0]); a2.x += f.x; a2.y += f.y;
      f = __half22float2(((const __half2*)&w6)[1]); a2.z += f.x; a2.w += f.y;
      f = __half22float2(((const __half2*)&w7)[0]); a3.x += f.x; a3.y += f.y;
      f = __half22float2(((const __half2*)&w7)[1]); a3.z += f.x; a3.w += f.y;
    }
    for (; j + 4 <= e0; j += 4) {
      int r0 = rows[j], r1 = rows[j + 1], r2 = rows[j + 2], r3 = rows[j + 3];
      float2 w0 = hwf2[(size_t)r0 * 16 + ql];
      float2 w1 = hwf2[(size_t)r1 * 16 + ql];
      float2 w2 = hwf2[(size_t)r2 * 16 + ql];
      float2 w3 = hwf2[(size_t)r3 * 16 + ql];
      float2 f;
      f = __half22float2(((const __half2*)&w0)[0]); a0.x += f.x; a0.y += f.y;
      f = __half22float2(((const __half2*)&w0)[1]); a0.z += f.x; a0.w += f.y;
      f = __half22float2(((const __half2*)&w1)[0]); a1.x += f.x; a1.y += f.y;
      f = __half22float2(((const __half2*)&w1)[1]); a1.z += f.x; a1.w += f.y;
      f = __half22float2(((const __half2*)&w2)[0]); a2.x += f.x; a2.y += f.y;
      f = __half22float2(((const __half2*)&w2)[1]); a2.z += f.x; a2.w += f.y;
      f = __half22float2(((const __half2*)&w3)[0]); a3.x += f.x; a3.y += f.y;
      f = __half22float2(((const __half2*)&w3)[1]); a3.z += f.x; a3.w += f.y;
    }
    for (; j < e0; j++) {
      int r = rows[j];
      float2 w = hwf2[(size_t)r * 16 + ql];
      float2 f;
      f = __half22float2(((const __half2*)&w)[0]); a0.x += f.x; a0.y += f.y;
      f = __half22float2(((const __half2*)&w)[1]); a0.z += f.x; a0.w += f.y;
    }
    float di = dinv[node];
    float ox = fmaxf(((a0.x + a1.x) + (a2.x + a3.x)) * di + bb.x, 0.f);
    float oy = fmaxf(((a0.y + a1.y) + (a2.y + a3.y)) * di + bb.y, 0.f);
    float oz = fmaxf(((a0.z + a1.z) + (a2.z + a3.z)) * di + bb.z, 0.f);
    float ow = fmaxf(((a0.w + a1.w) + (a2.w + a3.w)) * di + bb.w, 0.f);
    float2 st;
    ((__half2*)&st)[0] = __floats2half2_rn(ox, oy);
    ((__half2*)&st)[1] = __floats2half2_rn(oz, ow);
    ((float2*)h16)[(size_t)node * 16 + ql] = st;
  }
}

// ---- fused Set2Set: 1 graph/block (1024 blocks -> 4 blocks/CU TLP) -------
__global__ __launch_bounds__(256) void k_set2set(
    const __half* __restrict__ h16, const int* __restrict__ batch,
    const float* __restrict__ WT, const float* __restrict__ bih,
    const float* __restrict__ bhh, const float* __restrict__ W1,
    const float* __restrict__ b1, const float* __restrict__ W2,
    const float* __restrict__ b2, float* __restrict__ out) {
  int b = blockIdx.x, t = threadIdx.x;
  int wave = t >> 6, lane = t & 63;
  int q = lane >> 4, ql = lane & 15;
  int qid = (wave << 2) + q;  // 0..15
  __shared__ float2 hcf2[CROWS * 16];  // 16 KiB fp16 row cache
  __shared__ float qs[2 * DIM];
  __shared__ float hsl[DIM], csl[DIM];
  __shared__ float gates[4 * DIM];
  __shared__ float red[16 * DIM];
  __shared__ float lred[16], wmax[16];
  __shared__ int seg[2];
  const float2* h2 = (const float2*)h16;
  if (t < 2) {  // graph boundary via binary search on sorted batch
    int g = b + t;
    int lo = 0, hi = N_NODES;
    if (g == NGRAPH) lo = N_NODES;
    else while (lo < hi) { int mid = (lo + hi) >> 1; if (batch[mid] < g) lo = mid + 1; else hi = mid; }
    seg[t] = lo;
  }
  if (t < 2 * DIM) qs[t] = 0.f;
  if (t < DIM) { hsl[t] = 0.f; csl[t] = 0.f; }
  __syncthreads();
  int s = seg[0], eend = seg[1];
  int nc = min(eend - s, CROWS);
  for (int i = t; i < nc * 16; i += 256)
    hcf2[i] = h2[(size_t)(s + (i >> 4)) * 16 + (i & 15)];
  __syncthreads();
  float bsum = bih[t] + bhh[t];
  for (int step = 0; step < 3; step++) {
    // ---- LSTM cell: thread t computes gate t (coalesced WT reads) ----
    float g = bsum;
    if (step > 0) {  // step 0: q_star = hs = 0 -> matmul contributes nothing
      const float* wp = WT + t;
      float g1 = 0.f;
#pragma unroll 8
      for (int k = 0; k < 2 * DIM; k += 2) {
        g += qs[k] * wp[k * 4 * DIM];
        g1 += qs[k + 1] * wp[(k + 1) * 4 * DIM];
      }
#pragma unroll 8
      for (int k = 0; k < DIM; k += 2) {
        g += hsl[k] * wp[(2 * DIM + k) * 4 * DIM];
        g1 += hsl[k + 1] * wp[(2 * DIM + k + 1) * 4 * DIM];
      }
      g += g1;
    }
    gates[t] = g;
    __syncthreads();
    if (t < DIM) {
      float ig = sigmoidf(gates[t]);
      float fg = sigmoidf(gates[DIM + t]);
      float gg = tanhf(gates[2 * DIM + t]);
      float og = sigmoidf(gates[3 * DIM + t]);
      float c = fg * csl[t] + ig * gg;
      csl[t] = c;
      float hh = og * tanhf(c);
      hsl[t] = hh;
      qs[t] = hh;  // q half of q_star
    }
    __syncthreads();
    // ---- quarter-wave online softmax over LDS-cached rows ----
    float4 qf = *(const float4*)&hsl[4 * ql];
    float m_w = -INFINITY, l_w = 0.f;
    float4 racc = make_float4(0.f, 0.f, 0.f, 0.f);
    for (int j = s + qid; j < eend; j += 16) {
      int lj = j - s;
      float2 raw = (lj < CROWS) ? hcf2[lj * 16 + ql]
                                : h2[(size_t)j * 16 + ql];
      float2 f0 = __half22float2(((const __half2*)&raw)[0]);
      float2 f1 = __half22float2(((const __half2*)&raw)[1]);
      float p = f0.x * qf.x + f0.y * qf.y + f1.x * qf.z + f1.y * qf.w;
#pragma unroll
      for (int off = 1; off < 16; off <<= 1) p += __shfl_xor(p, off, 64);
      float m_new = fmaxf(m_w, p);
      float scale = __expf(m_w - m_new);  // first row: exp(-inf)=0
      float a = __expf(p - m_new);
      racc.x = racc.x * scale + a * f0.x;
      racc.y = racc.y * scale + a * f0.y;
      racc.z = racc.z * scale + a * f1.x;
      racc.w = racc.w * scale + a * f1.y;
      l_w = l_w * scale + a;
      m_w = m_new;
    }
    *(float4*)&red[qid * DIM + 4 * ql] = racc;
    if (ql == 0) { lred[qid] = l_w; wmax[qid] = m_w; }
    __syncthreads();
    if (t < DIM) {
      float m_b = -1e30f;  // floor avoids NaN for empty graphs
      for (int i = 0; i < 16; i++) m_b = fmaxf(m_b, wmax[i]);
      float r = 0.f, l = 0.f;
      for (int i = 0; i < 16; i++) {
        float e = __expf(wmax[i] - m_b);
        r += red[i * DIM + t] * e;
        l += lred[i] * e;
      }
      qs[DIM + t] = (l > 0.f) ? r / l : 0.f;
    }
    __syncthreads();
  }
  // ---- output MLP head ----
  if (t < DIM) {
    float acc = b1[t];
#pragma unroll
    for (int k = 0; k < 2 * DIM; k++) acc += qs[k] * W1[k * DIM + t];
    acc = fmaxf(acc, 0.f);
    float v = wsum(acc * W2[t]);
    if (t == 0) out[b] = v + b2[0];
  }
}

extern "C" void kernel_launch(void* const* d_in, const int* in_sizes, int n_in,
                              void* d_out, int out_size, void* d_ws, size_t ws_size,
                              hipStream_t stream) {
  const float* x    = (const float*)d_in[0];
  const int*   ei   = (const int*)d_in[1];
  const int*   batch= (const int*)d_in[2];
  const float* W0   = (const float*)d_in[3];
  const float* b0   = (const float*)d_in[4];
  const float* Wc   = (const float*)d_in[5];
  const float* bc   = (const float*)d_in[6];
  const float* Wih  = (const float*)d_in[7];
  const float* Whh  = (const float*)d_in[8];
  const float* bih  = (const float*)d_in[9];
  const float* bhh  = (const float*)d_in[10];
  const float* W1   = (const float*)d_in[11];
  const float* b1   = (const float*)d_in[12];
  const float* W2   = (const float*)d_in[13];
  const float* b2   = (const float*)d_in[14];
  float* out = (float*)d_out;

  __half* hw16 = (__half*)d_ws;                      // N*DIM halves (6.4 MB)
  __half* h16  = hw16 + (size_t)N_NODES * DIM;       // N*DIM halves (6.4 MB)
  float* dinv  = (float*)(h16 + (size_t)N_NODES * DIM);  // N floats
  float* WT    = dinv + N_NODES;                     // 192*256 floats
  int* gcur    = (int*)(WT + 3 * DIM * 4 * DIM);     // NBKB bucket counters
  int* deg     = gcur + NBKB;                        // N per-node in-degree
  int* pairs   = deg + N_NODES + 2;                  // NBKB*CAP packed edges (16B-aligned)

  hipMemsetAsync(gcur, 0, NBKB * sizeof(int), stream);
  k_bin<<<NBIN + 1, 1024, 0, stream>>>(ei, gcur, pairs, Wih, Whh, WT);
  k_lin0<<<NBKB, 256, 0, stream>>>(x, W0, b0, Wc, pairs, gcur, deg, dinv, hw16);
  k_agg<<<NBKB, 512, 0, stream>>>(pairs, gcur, deg, hw16, dinv, (const float4*)bc, h16);
  k_set2set<<<NGRAPH, 256, 0, stream>>>(h16, batch, WT, bih, bhh, W1, b1, W2, b2, out);
}